// Round 3
// baseline (20549.777 us; speedup 1.0000x reference)
//
#include <hip/hip_runtime.h>
#include <hip/hip_bf16.h>

// Seq2seq LSTM (enc 1024 steps -> dec 1024 steps, reversed, proj-before-update).
// 16 WGs x 256 thr. 8 groups x 16 batches; 2 WGs/group each own 512 of the 1024
// gate rows. f16 weight fragments persistent in VGPR/AGPR (320 regs/lane).
// R3 = R2 fixed: h-exchange via RELAXED agent-scope atomics (coherent at the
// coherence point, no fences -> no buffer_wbl2 L2 flush that made R1 5.2us/step).
// Flag = per-wave atomic_fetch_add after vmcnt(0); partner polls >= 4t.
// Own-tile MFMAs issued before the poll; decoder projection after the publish.

#define Bb 128
#define Tt 1024
#define Ff 64
#define Hh 256

typedef _Float16 h16;
typedef __attribute__((ext_vector_type(8))) _Float16 h16x8;
typedef __attribute__((ext_vector_type(4))) float f32x4;
typedef __attribute__((ext_vector_type(2))) unsigned long long u64x2;

// ws layout (f16 element offsets)
#define WENC_OFF 0          // 2*4*8*10*64*8 = 327680 f16
#define WDEC_OFF 327680
#define WOUT_OFF 655360     // 2*2*8*64*8 = 16384 f16
#define HBUF_OFF 671744     // 16 wg * 2 slots * 16 m * 128 col = 65536 f16
#define FLAGS_BYTE_OFF 1474560  // (671744+65536)*2, u32[16]

// v_exp_f32 computes 2^x -> sigmoid(x) = 1/(1+2^(-x*log2e))
__device__ __forceinline__ float sigm(float x) {
  return __builtin_amdgcn_rcpf(1.f + __builtin_amdgcn_exp2f(-1.442695041f * x));
}
__device__ __forceinline__ float tanh_f(float x) {
  return 2.f * __builtin_amdgcn_rcpf(1.f + __builtin_amdgcn_exp2f(-2.885390082f * x)) - 1.f;
}

// ---- prep: convert fp32 weights into f16 MFMA-fragment-ordered regions ----
__global__ void lstm_prep(const float* __restrict__ Wih_e, const float* __restrict__ Whh_e,
                          const float* __restrict__ Wih_d, const float* __restrict__ Whh_d,
                          const float* __restrict__ Wout, h16* __restrict__ ws16,
                          unsigned int* __restrict__ flags) {
  int e = blockIdx.x * 256 + threadIdx.x;
  if (e < 16) flags[e] = 0u;
  if (e < 655360) {
    int r = e;
    const float* Wih = Wih_e; const float* Whh = Whh_e;
    int off = WENC_OFF;
    if (r >= 327680) { r -= 327680; Wih = Wih_d; Whh = Whh_d; off = WDEC_OFF; }
    // r = ((((q*4+w)*8+nt)*10+kt)*64+lane)*8 + j
    int j    = r & 7;
    int lane = (r >> 3) & 63;
    int kt   = (r >> 9) % 10;
    int tmp  = (r >> 9) / 10;        // (q*4+w)*8+nt
    int nt   = tmp & 7;
    int w    = (tmp >> 3) & 3;
    int q    = tmp >> 5;
    int g = nt >> 1, ct = nt & 1;
    int col = q * 128 + w * 32 + ct * 16 + (lane & 15);
    int row = g * 256 + col;
    int k = kt * 32 + (lane >> 4) * 8 + j;
    float v = (k < 64) ? Wih[row * 64 + k] : Whh[row * 256 + (k - 64)];
    ws16[off + r] = (h16)v;
  } else if (e < 655360 + 16384) {
    int r = e - 655360;
    // r = (((q*2+wt)*8+kt)*64+lane)*8 + j
    int j    = r & 7;
    int lane = (r >> 3) & 63;
    int kt   = (r >> 9) & 7;
    int wt   = (r >> 12) & 1;
    int q    = (r >> 13) & 1;
    int f = q * 32 + wt * 16 + (lane & 15);
    int k = kt * 32 + (lane >> 4) * 8 + j;
    ws16[WOUT_OFF + r] = (h16)Wout[f * 256 + k];
  }
}

// ---- main persistent kernel ----
__global__ __launch_bounds__(256, 1) void lstm_main(
    const float* __restrict__ ts,
    const float* __restrict__ b_enc, const float* __restrict__ b_dec,
    const float* __restrict__ b_out,
    const h16* __restrict__ wsW, h16* __restrict__ hbuf,
    unsigned int* flags, float* __restrict__ out) {
  const int tid = threadIdx.x;
  const int wg = blockIdx.x;
  const int grp = wg & 7, q = wg >> 3;
  const int w = tid >> 6, lane = tid & 63;
  const int n16 = lane & 15, quad = lane >> 4;
  const int b0 = grp * 16;
  const int partner = wg ^ 8;

  __shared__ h16 xh[2][16][328];    // k: 0..63 x, 64..319 h
  __shared__ h16x8 woutLds[1024];

  // persistent weight fragments: 8 N-tiles x 10 K-tiles
  h16x8 wf[8][10];
  {
    const h16x8* wsrc = (const h16x8*)(wsW + WENC_OFF);
#pragma unroll
    for (int nt = 0; nt < 8; ++nt)
#pragma unroll
      for (int kt = 0; kt < 10; ++kt)
        wf[nt][kt] = wsrc[(((q * 4 + w) * 8 + nt) * 10 + kt) * 64 + lane];
  }
  float bias8[8];
#pragma unroll
  for (int nt = 0; nt < 8; ++nt) {
    int g = nt >> 1, ct = nt & 1;
    bias8[nt] = b_enc[g * 256 + q * 128 + w * 32 + ct * 16 + n16];
  }
  const float bo = b_out[q * 32 + w * 16 + n16];

  float c8[8];
#pragma unroll
  for (int i = 0; i < 8; ++i) c8[i] = 0.f;

  // zero h-region of xh[0]; stage x_0
  for (int i = tid; i < 16 * 264; i += 256) {
    int m = i / 264;
    xh[0][m][64 + (i - m * 264)] = (h16)0.f;
  }
  const int m_x = tid >> 4, ks_x = (tid & 15) * 4;
  {
    const f32x4 xv0 = *(const f32x4*)(ts + ((size_t)(b0 + m_x) * Tt + 0) * Ff + ks_x);
#pragma unroll
    for (int u = 0; u < 4; ++u) xh[0][m_x][ks_x + u] = (h16)xv0[u];
  }
  __syncthreads();

  for (int t = 0; t < 2048; ++t) {
    const int nb = t & 1, nxt = nb ^ 1;
    const bool dec = (t >= 1024);

    // phase switch: decoder weights + biases + W_out -> LDS
    if (t == 1024) {
      const h16x8* wsrc2 = (const h16x8*)(wsW + WDEC_OFF);
#pragma unroll
      for (int nt = 0; nt < 8; ++nt)
#pragma unroll
        for (int kt = 0; kt < 10; ++kt)
          wf[nt][kt] = wsrc2[(((q * 4 + w) * 8 + nt) * 10 + kt) * 64 + lane];
#pragma unroll
      for (int nt = 0; nt < 8; ++nt) {
        int g = nt >> 1, ct = nt & 1;
        bias8[nt] = b_dec[g * 256 + q * 128 + w * 32 + ct * 16 + n16];
      }
      const h16x8* wo = (const h16x8*)(wsW + WOUT_OFF) + q * 1024;
      for (int i = tid; i < 1024; i += 256) woutLds[i] = wo[i];
      __syncthreads();
    }

    // (C) own A-fragments: x + own h from LDS
    h16x8 a[10];
    const h16* xrow = &xh[nb][n16][0];
#pragma unroll
    for (int kt = 0; kt < 2; ++kt)
      a[kt] = *(const h16x8*)(xrow + kt * 32 + quad * 8);
    const int ownBase = (q == 0) ? 2 : 6;
    const int parBase = (q == 0) ? 6 : 2;
#pragma unroll
    for (int i = 0; i < 4; ++i)
      a[ownBase + i] = *(const h16x8*)(xrow + (ownBase + i) * 32 + quad * 8);

    // (D) x prefetch for t+1
    f32x4 xv;
#pragma unroll
    for (int u = 0; u < 4; ++u) xv[u] = 0.f;
    if (t + 1 < 2048) {
      int xi = (t + 1 < 1024) ? (t + 1) : (2047 - (t + 1));
      xv = *(const f32x4*)(ts + ((size_t)(b0 + m_x) * Tt + xi) * Ff + ks_x);
    }

    // (E) bias-init accs; 48 MFMAs over the 6 partner-independent tiles
    f32x4 acc[8];
#pragma unroll
    for (int nt = 0; nt < 8; ++nt) {
      f32x4 v; v[0] = bias8[nt]; v[1] = bias8[nt]; v[2] = bias8[nt]; v[3] = bias8[nt];
      acc[nt] = v;
    }
#pragma unroll
    for (int kt = 0; kt < 2; ++kt)
#pragma unroll
      for (int nt = 0; nt < 8; ++nt)
        acc[nt] = __builtin_amdgcn_mfma_f32_16x16x32_f16(a[kt], wf[nt][kt], acc[nt], 0, 0, 0);
#pragma unroll
    for (int i = 0; i < 4; ++i)
#pragma unroll
      for (int nt = 0; nt < 8; ++nt)
        acc[nt] = __builtin_amdgcn_mfma_f32_16x16x32_f16(a[ownBase + i], wf[nt][ownBase + i], acc[nt], 0, 0, 0);

    // (A) poll partner flag (relaxed agent atomic; no fences)
    if (t > 0) {
      unsigned int want = 4u * (unsigned int)t;
      while (__hip_atomic_load(&flags[partner], __ATOMIC_RELAXED,
                               __HIP_MEMORY_SCOPE_AGENT) < want) {}
      asm volatile("" ::: "memory");
      // (B) gather partner h fragments: 8 independent 8B relaxed atomic loads
      const unsigned long long* ps64 =
          (const unsigned long long*)(hbuf + ((size_t)partner * 2 + ((t + 1) & 1)) * 2048);
      const int gb = n16 * 32 + quad * 2;
      unsigned long long gld[8];
#pragma unroll
      for (int i = 0; i < 4; ++i) {
        gld[2 * i + 0] = __hip_atomic_load(&ps64[gb + i * 8 + 0], __ATOMIC_RELAXED,
                                           __HIP_MEMORY_SCOPE_AGENT);
        gld[2 * i + 1] = __hip_atomic_load(&ps64[gb + i * 8 + 1], __ATOMIC_RELAXED,
                                           __HIP_MEMORY_SCOPE_AGENT);
      }
#pragma unroll
      for (int i = 0; i < 4; ++i) {
        union { unsigned long long u[2]; h16x8 v; } cv;
        cv.u[0] = gld[2 * i + 0];
        cv.u[1] = gld[2 * i + 1];
        a[parBase + i] = cv.v;
      }
    } else {
      h16x8 z;
#pragma unroll
      for (int i = 0; i < 8; ++i) z[i] = (h16)0.f;
#pragma unroll
      for (int i = 0; i < 4; ++i) a[parBase + i] = z;
    }

    // (F) 32 MFMAs over partner tiles
#pragma unroll
    for (int i = 0; i < 4; ++i)
#pragma unroll
      for (int nt = 0; nt < 8; ++nt)
        acc[nt] = __builtin_amdgcn_mfma_f32_16x16x32_f16(a[parBase + i], wf[nt][parBase + i], acc[nt], 0, 0, 0);

    // (G) pointwise LSTM cell (fp32 c in regs)
    h16 hv[8];
#pragma unroll
    for (int ct = 0; ct < 2; ++ct)
#pragma unroll
      for (int r = 0; r < 4; ++r) {
        float i_ = sigm(acc[0 + ct][r]);
        float f_ = sigm(acc[2 + ct][r]);
        float g_ = tanh_f(acc[4 + ct][r]);
        float o_ = sigm(acc[6 + ct][r]);
        float cv = f_ * c8[ct * 4 + r] + i_ * g_;
        c8[ct * 4 + r] = cv;
        hv[ct * 4 + r] = (h16)(o_ * tanh_f(cv));
      }

    // (H) write h -> xh[nxt] own region; stage x_{t+1}
#pragma unroll
    for (int ct = 0; ct < 2; ++ct)
#pragma unroll
      for (int r = 0; r < 4; ++r) {
        int m = quad * 4 + r;
        xh[nxt][m][64 + q * 128 + w * 32 + ct * 16 + n16] = hv[ct * 4 + r];
      }
    if (t + 1 < 2048) {
#pragma unroll
      for (int u = 0; u < 4; ++u) xh[nxt][m_x][ks_x + u] = (h16)xv[u];
    }

    // (I) barrier: xh[nxt] complete (also orders next-iter frag reads)
    __syncthreads();

    // (J) repack own half from LDS (coalesced 16B) -> 2 relaxed atomic u64 stores
    {
      const int rm = tid >> 4, rp = tid & 15;
      u64x2 hval = *(const u64x2*)&xh[nxt][rm][64 + q * 128 + rp * 8];
      unsigned long long* hb64 =
          (unsigned long long*)(hbuf + ((size_t)wg * 2 + (t & 1)) * 2048);
      __hip_atomic_store(&hb64[tid * 2 + 0], hval[0], __ATOMIC_RELAXED,
                         __HIP_MEMORY_SCOPE_AGENT);
      __hip_atomic_store(&hb64[tid * 2 + 1], hval[1], __ATOMIC_RELAXED,
                         __HIP_MEMORY_SCOPE_AGENT);
    }

    // (K) wave-level publish: drain own stores, then one atomic add per wave
    asm volatile("s_waitcnt vmcnt(0)" ::: "memory");
    if (t < 2047 && (tid & 63) == 0)
      __hip_atomic_fetch_add(&flags[wg], 1u, __ATOMIC_RELAXED,
                             __HIP_MEMORY_SCOPE_AGENT);
    asm volatile("" ::: "memory");

    // (L) decoder projection (PRE-update h = a[2..9]) — off the critical path
    if (dec && w < 2) {
      f32x4 ao; ao[0] = bo; ao[1] = bo; ao[2] = bo; ao[3] = bo;
#pragma unroll
      for (int kt = 0; kt < 8; ++kt)
        ao = __builtin_amdgcn_mfma_f32_16x16x32_f16(a[2 + kt], woutLds[(w * 8 + kt) * 64 + lane], ao, 0, 0, 0);
      int tpos = 2047 - t;
      int f = q * 32 + w * 16 + n16;
#pragma unroll
      for (int r = 0; r < 4; ++r) {
        int m = quad * 4 + r;
        out[((size_t)(b0 + m) * Tt + tpos) * Ff + f] = ao[r];
      }
    }
  }
}

extern "C" void kernel_launch(void* const* d_in, const int* in_sizes, int n_in,
                              void* d_out, int out_size, void* d_ws, size_t ws_size,
                              hipStream_t stream) {
  const float* ts  = (const float*)d_in[0];
  const float* Wie = (const float*)d_in[1];
  const float* Whe = (const float*)d_in[2];
  const float* be  = (const float*)d_in[3];
  const float* Wid = (const float*)d_in[4];
  const float* Whd = (const float*)d_in[5];
  const float* bd  = (const float*)d_in[6];
  const float* Wo  = (const float*)d_in[7];
  const float* bo  = (const float*)d_in[8];

  h16* ws16 = (h16*)d_ws;
  unsigned int* flags = (unsigned int*)((char*)d_ws + FLAGS_BYTE_OFF);
  float* out = (float*)d_out;

  lstm_prep<<<2624, 256, 0, stream>>>(Wie, Whe, Wid, Whd, Wo, ws16, flags);
  lstm_main<<<16, 256, 0, stream>>>(ts, be, bd, bo, ws16, ws16 + HBUF_OFF, flags, out);
}

// Round 6
// 20000.998 us; speedup vs baseline: 1.0274x; 1.0274x over previous
//
#include <hip/hip_runtime.h>
#include <hip/hip_bf16.h>

// Seq2seq LSTM (enc 1024 -> dec 1024 reversed, proj-before-update).
// 16 WGs x 256 thr; pair (wg, wg^8) splits the 1024 gate rows; f16 weight
// fragments persistent in registers (320/lane). R6 transport: R3's PROVEN
// protocol (monotone >= flag poll, parity-buffered h slots, prep-zeroed flags)
// over plain sc0+sc1 (IF-point, cross-XCD-safe) loads/stores -- coalescable,
// no RMW atomics (R3's serialization), no fences (R1's wbl2 flush), no
// placement guess (R4), no equality race (R5 deadlock). Poll is one broadcast
// dwordx4 of 4 per-wave flag words + 32k-iter watchdog (hang -> visible fail).

#define Bb 128
#define Tt 1024
#define Ff 64
#define Hh 256

typedef _Float16 h16;
typedef __attribute__((ext_vector_type(8))) _Float16 h16x8;
typedef __attribute__((ext_vector_type(4))) float f32x4;
typedef __attribute__((ext_vector_type(4))) unsigned int u32x4;

// ws byte layout
#define WENC_OFF 0              // f16 units (327680 f16)
#define WDEC_OFF 327680
#define WOUT_OFF 655360         // (16384 f16)
#define HBUF_BYTE 1343488       // 16 wg * 2 slots * 4096 B
#define FLAGS_BYTE 1474560      // 16 wg * 64 B (4 u32: one per wave)

// v_exp_f32 computes 2^x -> sigmoid(x) = 1/(1+2^(-x*log2e))
__device__ __forceinline__ float sigm(float x) {
  return __builtin_amdgcn_rcpf(1.f + __builtin_amdgcn_exp2f(-1.442695041f * x));
}
__device__ __forceinline__ float tanh_f(float x) {
  return 2.f * __builtin_amdgcn_rcpf(1.f + __builtin_amdgcn_exp2f(-2.885390082f * x)) - 1.f;
}

// ---- IF-point (cross-XCD-safe) memory helpers: sc0 sc1 loads read at the IF
// coherence point; sc0 sc1 stores write through to it. Loads carry vmcnt(0)
// inside the asm block so results are valid before any C-level use.
__device__ __forceinline__ void st16_if(void* p, f32x4 v) {
  asm volatile("global_store_dwordx4 %0, %1, off sc0 sc1" :: "v"(p), "v"(v) : "memory");
}
__device__ __forceinline__ void st4_if(void* p, unsigned int v) {
  asm volatile("global_store_dword %0, %1, off sc0 sc1" :: "v"(p), "v"(v) : "memory");
}
__device__ __forceinline__ u32x4 ld_flags_if(const void* p) {
  u32x4 r;
  asm volatile("global_load_dwordx4 %0, %1, off sc0 sc1\n\ts_waitcnt vmcnt(0)"
               : "=&v"(r) : "v"(p) : "memory");
  return r;
}
__device__ __forceinline__ void gather4_if(const char* p, f32x4& g0, f32x4& g1,
                                           f32x4& g2, f32x4& g3) {
  asm volatile(
      "global_load_dwordx4 %0, %4, off sc0 sc1\n\t"
      "global_load_dwordx4 %1, %5, off sc0 sc1\n\t"
      "global_load_dwordx4 %2, %6, off sc0 sc1\n\t"
      "global_load_dwordx4 %3, %7, off sc0 sc1\n\t"
      "s_waitcnt vmcnt(0)"
      : "=&v"(g0), "=&v"(g1), "=&v"(g2), "=&v"(g3)
      : "v"(p), "v"(p + 64), "v"(p + 128), "v"(p + 192)
      : "memory");
}
__device__ __forceinline__ void drain_vm() {
  asm volatile("s_waitcnt vmcnt(0)" ::: "memory");
}

// ---- prep: weights -> f16 MFMA fragments; zero flag lines THROUGH to IF ----
__global__ void lstm_prep(const float* __restrict__ Wih_e, const float* __restrict__ Whh_e,
                          const float* __restrict__ Wih_d, const float* __restrict__ Whh_d,
                          const float* __restrict__ Wout, char* __restrict__ wsB) {
  int e = blockIdx.x * 256 + threadIdx.x;
  h16* ws16 = (h16*)wsB;
  if (e < 256) st4_if((unsigned int*)(wsB + FLAGS_BYTE) + e, 0u);
  if (e < 655360) {
    int r = e;
    const float* Wih = Wih_e; const float* Whh = Whh_e;
    int off = WENC_OFF;
    if (r >= 327680) { r -= 327680; Wih = Wih_d; Whh = Whh_d; off = WDEC_OFF; }
    // r = ((((q*4+w)*8+nt)*10+kt)*64+lane)*8 + j
    int j    = r & 7;
    int lane = (r >> 3) & 63;
    int kt   = (r >> 9) % 10;
    int tmp  = (r >> 9) / 10;
    int nt   = tmp & 7;
    int w    = (tmp >> 3) & 3;
    int q    = tmp >> 5;
    int g = nt >> 1, ct = nt & 1;
    int col = q * 128 + w * 32 + ct * 16 + (lane & 15);
    int row = g * 256 + col;
    int k = kt * 32 + (lane >> 4) * 8 + j;
    float v = (k < 64) ? Wih[row * 64 + k] : Whh[row * 256 + (k - 64)];
    ws16[off + r] = (h16)v;
  } else if (e < 655360 + 16384) {
    int r = e - 655360;
    int j    = r & 7;
    int lane = (r >> 3) & 63;
    int kt   = (r >> 9) & 7;
    int wt   = (r >> 12) & 1;
    int q    = (r >> 13) & 1;
    int f = q * 32 + wt * 16 + (lane & 15);
    int k = kt * 32 + (lane >> 4) * 8 + j;
    ws16[WOUT_OFF + r] = (h16)Wout[f * 256 + k];
  }
}

// ---- main persistent kernel ----
__global__ __launch_bounds__(256, 1) void lstm_main(
    const float* __restrict__ ts,
    const float* __restrict__ b_enc, const float* __restrict__ b_dec,
    const float* __restrict__ b_out,
    char* __restrict__ wsB, float* __restrict__ out) {
  const int tid = threadIdx.x;
  const int wg = blockIdx.x;
  const int grp = wg & 7, q = wg >> 3;
  const int w = tid >> 6, lane = tid & 63;
  const int n16 = lane & 15, quad = lane >> 4;
  const int b0 = grp * 16;
  const int partner = wg ^ 8;

  const h16* wsW = (const h16*)wsB;
  char* hbufB = wsB + HBUF_BYTE;
  char* flagsB = wsB + FLAGS_BYTE;

  __shared__ h16 xh[2][16][328];    // k: 0..63 x, 64..319 h (proven R3 layout)
  __shared__ h16x8 woutLds[1024];

  // persistent weight fragments: 8 N-tiles x 10 K-tiles
  h16x8 wf[8][10];
  {
    const h16x8* wsrc = (const h16x8*)(wsW + WENC_OFF);
#pragma unroll
    for (int nt = 0; nt < 8; ++nt)
#pragma unroll
      for (int kt = 0; kt < 10; ++kt)
        wf[nt][kt] = wsrc[(((q * 4 + w) * 8 + nt) * 10 + kt) * 64 + lane];
  }
  float bias8[8];
#pragma unroll
  for (int nt = 0; nt < 8; ++nt) {
    int g = nt >> 1, ct = nt & 1;
    bias8[nt] = b_enc[g * 256 + q * 128 + w * 32 + ct * 16 + n16];
  }
  const float bo = b_out[q * 32 + w * 16 + n16];

  float c8[8];
#pragma unroll
  for (int i = 0; i < 8; ++i) c8[i] = 0.f;

  // zero h-region of xh[0]; stage x_0
  for (int i = tid; i < 16 * 264; i += 256) {
    int m = i / 264;
    xh[0][m][64 + (i - m * 264)] = (h16)0.f;
  }
  const int m_x = tid >> 4, ks_x = (tid & 15) * 4;
  {
    const f32x4 xv0 = *(const f32x4*)(ts + ((size_t)(b0 + m_x) * Tt + 0) * Ff + ks_x);
#pragma unroll
    for (int u = 0; u < 4; ++u) xh[0][m_x][ks_x + u] = (h16)xv0[u];
  }
  __syncthreads();

  for (int t = 0; t < 2048; ++t) {
    const int nb = t & 1, nxt = nb ^ 1;
    const bool dec = (t >= 1024);

    if (t == 1024) {   // phase switch: decoder weights/biases + W_out
      const h16x8* wsrc2 = (const h16x8*)(wsW + WDEC_OFF);
#pragma unroll
      for (int nt = 0; nt < 8; ++nt)
#pragma unroll
        for (int kt = 0; kt < 10; ++kt)
          wf[nt][kt] = wsrc2[(((q * 4 + w) * 8 + nt) * 10 + kt) * 64 + lane];
#pragma unroll
      for (int nt = 0; nt < 8; ++nt) {
        int g = nt >> 1, ct = nt & 1;
        bias8[nt] = b_dec[g * 256 + q * 128 + w * 32 + ct * 16 + n16];
      }
      const h16x8* wo = (const h16x8*)(wsW + WOUT_OFF) + q * 1024;
      for (int i = tid; i < 1024; i += 256) woutLds[i] = wo[i];
      __syncthreads();
    }

    // (C) own A-fragments from LDS
    h16x8 a[10];
    const h16* xrow = &xh[nb][n16][0];
#pragma unroll
    for (int kt = 0; kt < 2; ++kt)
      a[kt] = *(const h16x8*)(xrow + kt * 32 + quad * 8);
    const int ownBase = (q == 0) ? 2 : 6;
    const int parBase = (q == 0) ? 6 : 2;
#pragma unroll
    for (int i = 0; i < 4; ++i)
      a[ownBase + i] = *(const h16x8*)(xrow + (ownBase + i) * 32 + quad * 8);

    // (D) x prefetch for t+1
    f32x4 xv;
#pragma unroll
    for (int u = 0; u < 4; ++u) xv[u] = 0.f;
    if (t + 1 < 2048) {
      int xi = (t + 1 < 1024) ? (t + 1) : (2047 - (t + 1));
      xv = __builtin_nontemporal_load(
          (const f32x4*)(ts + ((size_t)(b0 + m_x) * Tt + xi) * Ff + ks_x));
    }

    // (E) bias-init accs; 48 partner-independent MFMAs (hide poll+gather)
    f32x4 acc[8];
#pragma unroll
    for (int nt = 0; nt < 8; ++nt) {
      f32x4 v; v[0] = bias8[nt]; v[1] = bias8[nt]; v[2] = bias8[nt]; v[3] = bias8[nt];
      acc[nt] = v;
    }
#pragma unroll
    for (int kt = 0; kt < 2; ++kt)
#pragma unroll
      for (int nt = 0; nt < 8; ++nt)
        acc[nt] = __builtin_amdgcn_mfma_f32_16x16x32_f16(a[kt], wf[nt][kt], acc[nt], 0, 0, 0);
#pragma unroll
    for (int i = 0; i < 4; ++i)
#pragma unroll
      for (int nt = 0; nt < 8; ++nt)
        acc[nt] = __builtin_amdgcn_mfma_f32_16x16x32_f16(a[ownBase + i], wf[nt][ownBase + i], acc[nt], 0, 0, 0);

    // (A) MONOTONE poll: one broadcast dwordx4 of partner's 4 wave-flags,
    // all >= t. Watchdog makes any protocol bug a visible failure, not a hang.
    if (t > 0) {
      const char* fb = flagsB + partner * 64;
      const unsigned int want = (unsigned int)t;
      int guard = 0;
      for (;;) {
        u32x4 f = ld_flags_if(fb);
        if ((f[0] >= want) & (f[1] >= want) & (f[2] >= want) & (f[3] >= want)) break;
        if (++guard > (1 << 15)) break;   // fail loud (absmax), never hang
      }
      // (B) gather partner h fragments (64B/lane, one asm block w/ vmcnt(0))
      const char* ps = hbufB + ((size_t)partner * 2 + ((t + 1) & 1)) * 4096
                     + n16 * 256 + quad * 16;
      f32x4 g0, g1, g2, g3;
      gather4_if(ps, g0, g1, g2, g3);
      union { f32x4 fv; h16x8 hv; } cv0, cv1, cv2, cv3;
      cv0.fv = g0; cv1.fv = g1; cv2.fv = g2; cv3.fv = g3;
      a[parBase + 0] = cv0.hv;
      a[parBase + 1] = cv1.hv;
      a[parBase + 2] = cv2.hv;
      a[parBase + 3] = cv3.hv;
    } else {
      h16x8 z;
#pragma unroll
      for (int i = 0; i < 8; ++i) z[i] = (h16)0.f;
#pragma unroll
      for (int i = 0; i < 4; ++i) a[parBase + i] = z;
    }

    // (F) 32 partner-tile MFMAs
#pragma unroll
    for (int i = 0; i < 4; ++i)
#pragma unroll
      for (int nt = 0; nt < 8; ++nt)
        acc[nt] = __builtin_amdgcn_mfma_f32_16x16x32_f16(a[parBase + i], wf[nt][parBase + i], acc[nt], 0, 0, 0);

    // (G) pointwise LSTM cell (fp32 c in regs)
    h16 hv[8];
#pragma unroll
    for (int ct = 0; ct < 2; ++ct)
#pragma unroll
      for (int r = 0; r < 4; ++r) {
        float i_ = sigm(acc[0 + ct][r]);
        float f_ = sigm(acc[2 + ct][r]);
        float g_ = tanh_f(acc[4 + ct][r]);
        float o_ = sigm(acc[6 + ct][r]);
        float cvv = f_ * c8[ct * 4 + r] + i_ * g_;
        c8[ct * 4 + r] = cvv;
        hv[ct * 4 + r] = (h16)(o_ * tanh_f(cvv));
      }

    // (H) h -> xh[nxt] own region; stage x_{t+1}
#pragma unroll
    for (int ct = 0; ct < 2; ++ct)
#pragma unroll
      for (int r = 0; r < 4; ++r) {
        int m = quad * 4 + r;
        xh[nxt][m][64 + q * 128 + w * 32 + ct * 16 + n16] = hv[ct * 4 + r];
      }
    if (t + 1 < 2048) {
#pragma unroll
      for (int u = 0; u < 4; ++u) xh[nxt][m_x][ks_x + u] = (h16)xv[u];
    }

    // (I) barrier: xh[nxt] complete (also orders next-iter LDS reads)
    __syncthreads();

    // (J) repack own half (coalesced 16B/lane) -> parity slot; (K) release:
    // per-wave vmcnt(0) drain (R3-proven ordering at IF), then wave flag.
    if (t < 2047) {
      const int rm = tid >> 4, rp = tid & 15;
      union { f32x4 fv; h16x8 hv; } pk;
      pk.hv = *(const h16x8*)&xh[nxt][rm][64 + q * 128 + rp * 8];
      char* hb = hbufB + ((size_t)wg * 2 + (t & 1)) * 4096;
      st16_if(hb + tid * 16, pk.fv);
      drain_vm();
      if ((tid & 63) == 0)
        st4_if(flagsB + wg * 64 + w * 4, (unsigned int)(t + 1));
    }

    // (L) decoder projection (PRE-update h = a[2..9]) — off the critical path
    if (dec && w < 2) {
      f32x4 ao; ao[0] = bo; ao[1] = bo; ao[2] = bo; ao[3] = bo;
#pragma unroll
      for (int kt = 0; kt < 8; ++kt)
        ao = __builtin_amdgcn_mfma_f32_16x16x32_f16(a[2 + kt], woutLds[(w * 8 + kt) * 64 + lane], ao, 0, 0, 0);
      int tpos = 2047 - t;
      int f = q * 32 + w * 16 + n16;
#pragma unroll
      for (int r = 0; r < 4; ++r) {
        int m = quad * 4 + r;
        __builtin_nontemporal_store(ao[r], out + ((size_t)(b0 + m) * Tt + tpos) * Ff + f);
      }
    }
  }
}

extern "C" void kernel_launch(void* const* d_in, const int* in_sizes, int n_in,
                              void* d_out, int out_size, void* d_ws, size_t ws_size,
                              hipStream_t stream) {
  const float* ts  = (const float*)d_in[0];
  const float* Wie = (const float*)d_in[1];
  const float* Whe = (const float*)d_in[2];
  const float* be  = (const float*)d_in[3];
  const float* Wid = (const float*)d_in[4];
  const float* Whd = (const float*)d_in[5];
  const float* bd  = (const float*)d_in[6];
  const float* Wo  = (const float*)d_in[7];
  const float* bo  = (const float*)d_in[8];

  char* wsB = (char*)d_ws;
  float* out = (float*)d_out;

  lstm_prep<<<2624, 256, 0, stream>>>(Wie, Whe, Wid, Whd, Wo, wsB);
  lstm_main<<<16, 256, 0, stream>>>(ts, be, bd, bo, wsB, out);
}

// Round 7
// 19624.857 us; speedup vs baseline: 1.0471x; 1.0192x over previous
//
#include <hip/hip_runtime.h>
#include <hip/hip_bf16.h>

// Seq2seq LSTM (enc 1024 -> dec 1024 reversed, proj-before-update).
// 16 WGs x 256 thr; pair (wg, wg^8) splits the 1024 gate rows; f16 weight
// fragments persistent in registers. R7: same PROVEN R6 protocol (monotone >=
// flag, parity slots, sc0 sc1 IF-point transport, watchdog) but transaction-
// minimized: poll by lane 0 only (+barrier release), gather ONCE per WG
// (256 thr x 16B into LDS partner region; R6 had every wave redundantly load
// the same 4KB = 4x txns), single per-WG flag stored by tid0 after WG drain.
// Txn model from R3/R6 equality: uncached lane-requests ~12cyc each, no
// coalescing -> R6 ~1900 txns/step ~ 9.8us/step; R7 ~520 txns/step.

#define Bb 128
#define Tt 1024
#define Ff 64
#define Hh 256

typedef _Float16 h16;
typedef __attribute__((ext_vector_type(8))) _Float16 h16x8;
typedef __attribute__((ext_vector_type(4))) float f32x4;

// ws byte layout
#define WENC_OFF 0              // f16 units (327680 f16)
#define WDEC_OFF 327680
#define WOUT_OFF 655360         // (16384 f16)
#define HBUF_BYTE 1343488       // 16 wg * 2 slots * 4096 B
#define FLAGS_BYTE 1474560      // 16 wg * 64 B (1 u32 per wg, own line)

// v_exp_f32 computes 2^x -> sigmoid(x) = 1/(1+2^(-x*log2e))
__device__ __forceinline__ float sigm(float x) {
  return __builtin_amdgcn_rcpf(1.f + __builtin_amdgcn_exp2f(-1.442695041f * x));
}
__device__ __forceinline__ float tanh_f(float x) {
  return 2.f * __builtin_amdgcn_rcpf(1.f + __builtin_amdgcn_exp2f(-2.885390082f * x)) - 1.f;
}

// ---- IF-point (cross-XCD-safe) helpers; loads carry their own vmcnt(0) ----
__device__ __forceinline__ void st16_if(void* p, f32x4 v) {
  asm volatile("global_store_dwordx4 %0, %1, off sc0 sc1" :: "v"(p), "v"(v) : "memory");
}
__device__ __forceinline__ void st4_if(void* p, unsigned int v) {
  asm volatile("global_store_dword %0, %1, off sc0 sc1" :: "v"(p), "v"(v) : "memory");
}
__device__ __forceinline__ unsigned int ld_flag_if(const void* p) {
  unsigned int r;
  asm volatile("global_load_dword %0, %1, off sc0 sc1\n\ts_waitcnt vmcnt(0)"
               : "=&v"(r) : "v"(p) : "memory");
  return r;
}
__device__ __forceinline__ f32x4 ld16_if(const void* p) {
  f32x4 r;
  asm volatile("global_load_dwordx4 %0, %1, off sc0 sc1\n\ts_waitcnt vmcnt(0)"
               : "=&v"(r) : "v"(p) : "memory");
  return r;
}
__device__ __forceinline__ void drain_vm() {
  asm volatile("s_waitcnt vmcnt(0)" ::: "memory");
}

// ---- prep: weights -> f16 MFMA fragments; zero flag lines THROUGH to IF ----
__global__ void lstm_prep(const float* __restrict__ Wih_e, const float* __restrict__ Whh_e,
                          const float* __restrict__ Wih_d, const float* __restrict__ Whh_d,
                          const float* __restrict__ Wout, char* __restrict__ wsB) {
  int e = blockIdx.x * 256 + threadIdx.x;
  h16* ws16 = (h16*)wsB;
  if (e < 256) st4_if((unsigned int*)(wsB + FLAGS_BYTE) + e, 0u);
  if (e < 655360) {
    int r = e;
    const float* Wih = Wih_e; const float* Whh = Whh_e;
    int off = WENC_OFF;
    if (r >= 327680) { r -= 327680; Wih = Wih_d; Whh = Whh_d; off = WDEC_OFF; }
    // r = ((((q*4+w)*8+nt)*10+kt)*64+lane)*8 + j
    int j    = r & 7;
    int lane = (r >> 3) & 63;
    int kt   = (r >> 9) % 10;
    int tmp  = (r >> 9) / 10;
    int nt   = tmp & 7;
    int w    = (tmp >> 3) & 3;
    int q    = tmp >> 5;
    int g = nt >> 1, ct = nt & 1;
    int col = q * 128 + w * 32 + ct * 16 + (lane & 15);
    int row = g * 256 + col;
    int k = kt * 32 + (lane >> 4) * 8 + j;
    float v = (k < 64) ? Wih[row * 64 + k] : Whh[row * 256 + (k - 64)];
    ws16[off + r] = (h16)v;
  } else if (e < 655360 + 16384) {
    int r = e - 655360;
    int j    = r & 7;
    int lane = (r >> 3) & 63;
    int kt   = (r >> 9) & 7;
    int wt   = (r >> 12) & 1;
    int q    = (r >> 13) & 1;
    int f = q * 32 + wt * 16 + (lane & 15);
    int k = kt * 32 + (lane >> 4) * 8 + j;
    ws16[WOUT_OFF + r] = (h16)Wout[f * 256 + k];
  }
}

// ---- main persistent kernel ----
__global__ __launch_bounds__(256, 1) void lstm_main(
    const float* __restrict__ ts,
    const float* __restrict__ b_enc, const float* __restrict__ b_dec,
    const float* __restrict__ b_out,
    char* __restrict__ wsB, float* __restrict__ out) {
  const int tid = threadIdx.x;
  const int wg = blockIdx.x;
  const int grp = wg & 7, q = wg >> 3;
  const int w = tid >> 6, lane = tid & 63;
  const int n16 = lane & 15, quad = lane >> 4;
  const int b0 = grp * 16;
  const int partner = wg ^ 8;

  const h16* wsW = (const h16*)wsB;
  char* hbufB = wsB + HBUF_BYTE;
  char* flagsB = wsB + FLAGS_BYTE;

  __shared__ h16 xh[2][16][328];    // k: 0..63 x, 64..319 h (proven layout)
  __shared__ h16x8 woutLds[1024];

  // persistent weight fragments: 8 N-tiles x 10 K-tiles
  h16x8 wf[8][10];
  {
    const h16x8* wsrc = (const h16x8*)(wsW + WENC_OFF);
#pragma unroll
    for (int nt = 0; nt < 8; ++nt)
#pragma unroll
      for (int kt = 0; kt < 10; ++kt)
        wf[nt][kt] = wsrc[(((q * 4 + w) * 8 + nt) * 10 + kt) * 64 + lane];
  }
  float bias8[8];
#pragma unroll
  for (int nt = 0; nt < 8; ++nt) {
    int g = nt >> 1, ct = nt & 1;
    bias8[nt] = b_enc[g * 256 + q * 128 + w * 32 + ct * 16 + n16];
  }
  const float bo = b_out[q * 32 + w * 16 + n16];

  float c8[8];
#pragma unroll
  for (int i = 0; i < 8; ++i) c8[i] = 0.f;

  // zero full h-region of xh[0] (both halves -> t=0 partner frags are 0); x_0
  for (int i = tid; i < 16 * 264; i += 256) {
    int m = i / 264;
    xh[0][m][64 + (i - m * 264)] = (h16)0.f;
  }
  const int m_x = tid >> 4, ks_x = (tid & 15) * 4;
  {
    const f32x4 xv0 = *(const f32x4*)(ts + ((size_t)(b0 + m_x) * Tt + 0) * Ff + ks_x);
#pragma unroll
    for (int u = 0; u < 4; ++u) xh[0][m_x][ks_x + u] = (h16)xv0[u];
  }
  __syncthreads();

  for (int t = 0; t < 2048; ++t) {
    const int nb = t & 1, nxt = nb ^ 1;
    const bool dec = (t >= 1024);

    if (t == 1024) {   // phase switch: decoder weights/biases + W_out
      const h16x8* wsrc2 = (const h16x8*)(wsW + WDEC_OFF);
#pragma unroll
      for (int nt = 0; nt < 8; ++nt)
#pragma unroll
        for (int kt = 0; kt < 10; ++kt)
          wf[nt][kt] = wsrc2[(((q * 4 + w) * 8 + nt) * 10 + kt) * 64 + lane];
#pragma unroll
      for (int nt = 0; nt < 8; ++nt) {
        int g = nt >> 1, ct = nt & 1;
        bias8[nt] = b_dec[g * 256 + q * 128 + w * 32 + ct * 16 + n16];
      }
      const h16x8* wo = (const h16x8*)(wsW + WOUT_OFF) + q * 1024;
      for (int i = tid; i < 1024; i += 256) woutLds[i] = wo[i];
      __syncthreads();
    }

    // (C) own A-fragments (x + own h) from LDS
    h16x8 a[10];
    const h16* xrow = &xh[nb][n16][0];
#pragma unroll
    for (int kt = 0; kt < 2; ++kt)
      a[kt] = *(const h16x8*)(xrow + kt * 32 + quad * 8);
    const int ownBase = (q == 0) ? 2 : 6;
    const int parBase = (q == 0) ? 6 : 2;
#pragma unroll
    for (int i = 0; i < 4; ++i)
      a[ownBase + i] = *(const h16x8*)(xrow + (ownBase + i) * 32 + quad * 8);

    // (D) x prefetch for t+1 (normal cached load)
    f32x4 xv;
#pragma unroll
    for (int u = 0; u < 4; ++u) xv[u] = 0.f;
    if (t + 1 < 2048) {
      int xi = (t + 1 < 1024) ? (t + 1) : (2047 - (t + 1));
      xv = *(const f32x4*)(ts + ((size_t)(b0 + m_x) * Tt + xi) * Ff + ks_x);
    }

    // (E) bias-init accs; 48 partner-independent MFMAs (overlap poll latency)
    f32x4 acc[8];
#pragma unroll
    for (int nt = 0; nt < 8; ++nt) {
      f32x4 v; v[0] = bias8[nt]; v[1] = bias8[nt]; v[2] = bias8[nt]; v[3] = bias8[nt];
      acc[nt] = v;
    }
#pragma unroll
    for (int kt = 0; kt < 2; ++kt)
#pragma unroll
      for (int nt = 0; nt < 8; ++nt)
        acc[nt] = __builtin_amdgcn_mfma_f32_16x16x32_f16(a[kt], wf[nt][kt], acc[nt], 0, 0, 0);
#pragma unroll
    for (int i = 0; i < 4; ++i)
#pragma unroll
      for (int nt = 0; nt < 8; ++nt)
        acc[nt] = __builtin_amdgcn_mfma_f32_16x16x32_f16(a[ownBase + i], wf[nt][ownBase + i], acc[nt], 0, 0, 0);

    // (A) poll: LANE 0 ONLY spins on partner's single flag word (monotone >=,
    // watchdog -> visible fail not hang), barrier releases the WG.
    if (t > 0) {
      if (tid == 0) {
        const char* fb = flagsB + partner * 64;
        const unsigned int want = (unsigned int)t;
        int guard = 0;
        for (;;) {
          unsigned int f = ld_flag_if(fb);
          if (f >= want) break;
          if (++guard > (1 << 16)) break;
        }
      }
    }
    __syncthreads();

    // (B) gather ONCE per WG: 256 threads x 16B -> xh[nb] partner region
    if (t > 0) {
      const char* ps = hbufB + ((size_t)partner * 2 + ((t + 1) & 1)) * 4096 + tid * 16;
      f32x4 g = ld16_if(ps);
      union { f32x4 fv; h16x8 hv; } cu; cu.fv = g;
      const int gm = tid >> 4, gp = tid & 15;
      *(h16x8*)&xh[nb][gm][64 + (q ^ 1) * 128 + gp * 8] = cu.hv;
    }
    __syncthreads();

    // partner A-fragments from LDS (zeroed region at t=0)
#pragma unroll
    for (int i = 0; i < 4; ++i)
      a[parBase + i] = *(const h16x8*)(xrow + (parBase + i) * 32 + quad * 8);

    // (F) 32 partner-tile MFMAs
#pragma unroll
    for (int i = 0; i < 4; ++i)
#pragma unroll
      for (int nt = 0; nt < 8; ++nt)
        acc[nt] = __builtin_amdgcn_mfma_f32_16x16x32_f16(a[parBase + i], wf[nt][parBase + i], acc[nt], 0, 0, 0);

    // (G) pointwise LSTM cell (fp32 c in regs)
    h16 hv[8];
#pragma unroll
    for (int ct = 0; ct < 2; ++ct)
#pragma unroll
      for (int r = 0; r < 4; ++r) {
        float i_ = sigm(acc[0 + ct][r]);
        float f_ = sigm(acc[2 + ct][r]);
        float g_ = tanh_f(acc[4 + ct][r]);
        float o_ = sigm(acc[6 + ct][r]);
        float cvv = f_ * c8[ct * 4 + r] + i_ * g_;
        c8[ct * 4 + r] = cvv;
        hv[ct * 4 + r] = (h16)(o_ * tanh_f(cvv));
      }

    // (H) h -> xh[nxt] own region; stage x_{t+1}
#pragma unroll
    for (int ct = 0; ct < 2; ++ct)
#pragma unroll
      for (int r = 0; r < 4; ++r) {
        int m = quad * 4 + r;
        xh[nxt][m][64 + q * 128 + w * 32 + ct * 16 + n16] = hv[ct * 4 + r];
      }
    if (t + 1 < 2048) {
#pragma unroll
      for (int u = 0; u < 4; ++u) xh[nxt][m_x][ks_x + u] = (h16)xv[u];
    }

    // (I) barrier: xh[nxt] complete before repack read
    __syncthreads();

    // (J) publish own half (256 x 16B sc1 stores) + per-wave drain
    if (t < 2047) {
      const int rm = tid >> 4, rp = tid & 15;
      union { f32x4 fv; h16x8 hv; } pk;
      pk.hv = *(const h16x8*)&xh[nxt][rm][64 + q * 128 + rp * 8];
      char* hb = hbufB + ((size_t)wg * 2 + (t & 1)) * 4096;
      st16_if(hb + tid * 16, pk.fv);
      drain_vm();
    }
    // (K) barrier = all waves drained; ONE flag store by tid0
    __syncthreads();
    if (t < 2047 && tid == 0)
      st4_if(flagsB + wg * 64, (unsigned int)(t + 1));

    // (L) decoder projection (PRE-update h = a[2..9]) — off the critical path
    if (dec && w < 2) {
      f32x4 ao; ao[0] = bo; ao[1] = bo; ao[2] = bo; ao[3] = bo;
#pragma unroll
      for (int kt = 0; kt < 8; ++kt)
        ao = __builtin_amdgcn_mfma_f32_16x16x32_f16(a[2 + kt], woutLds[(w * 8 + kt) * 64 + lane], ao, 0, 0, 0);
      int tpos = 2047 - t;
      int f = q * 32 + w * 16 + n16;
#pragma unroll
      for (int r = 0; r < 4; ++r) {
        int m = quad * 4 + r;
        __builtin_nontemporal_store(ao[r], out + ((size_t)(b0 + m) * Tt + tpos) * Ff + f);
      }
    }
  }
}

extern "C" void kernel_launch(void* const* d_in, const int* in_sizes, int n_in,
                              void* d_out, int out_size, void* d_ws, size_t ws_size,
                              hipStream_t stream) {
  const float* ts  = (const float*)d_in[0];
  const float* Wie = (const float*)d_in[1];
  const float* Whe = (const float*)d_in[2];
  const float* be  = (const float*)d_in[3];
  const float* Wid = (const float*)d_in[4];
  const float* Whd = (const float*)d_in[5];
  const float* bd  = (const float*)d_in[6];
  const float* Wo  = (const float*)d_in[7];
  const float* bo  = (const float*)d_in[8];

  char* wsB = (char*)d_ws;
  float* out = (float*)d_out;

  lstm_prep<<<2624, 256, 0, stream>>>(Wie, Whe, Wid, Whd, Wo, wsB);
  lstm_main<<<16, 256, 0, stream>>>(ts, be, bd, bo, wsB, out);
}